// Round 16
// baseline (79.848 us; speedup 1.0000x reference)
//
#include <hip/hip_runtime.h>
#include <hip/hip_bf16.h>

#define BATCH  512
#define TT     16
#define NN     22
#define CC     64
#define DD     1024          // TT*CC
#define NB     3
#define NTHR   512
#define WPAD   40            // Wh row stride (u16): 80B rows, 16B-aligned

typedef __bf16 bf16x8 __attribute__((ext_vector_type(8)));
typedef float  f32x4  __attribute__((ext_vector_type(4)));
typedef float  f32x16 __attribute__((ext_vector_type(16)));

__device__ __forceinline__ unsigned bf16rne(float x) {
  unsigned u = __float_as_uint(x);
  u += 0x7fffu + ((u >> 16) & 1u);
  return u >> 16;
}
__device__ __forceinline__ unsigned pack2(float a, float b) {
  return bf16rne(a) | (bf16rne(b) << 16);
}
// xs subtiled layout: 128B blocks of [4 m][16 d] bf16, block index (d>>4)*6 + (m>>2)
__device__ __forceinline__ unsigned xoff(unsigned m, unsigned d) {
  return ((d >> 4) * 6u + (m >> 2)) * 64u + (m & 3u) * 16u + (d & 15u);
}

__global__ __launch_bounds__(NTHR) void mbdsca_fused(
    const float* __restrict__ x,        // [B, T, N, C]
    const float* __restrict__ adj,      // [N, N]
    const float* __restrict__ btemps,   // [NB]
    const float* __restrict__ flogits,  // [2, NB]
    float* __restrict__ out)            // [B*N*D] xb ++ [N*N] A
{
  __shared__ unsigned short xs[6 * 64 * 64];   // 49152 B, 24 m-rows (22 real + 2 zero)
  __shared__ float As[NN][NN];
  __shared__ float G[NN][NN];                  // Gram (ds_add_f32 accumulated)
  __shared__ float attB[NB][NN][NN];           // exp(att - rowmax) values
  __shared__ unsigned short Wh[32][WPAD];      // combined weights, bf16 (pad rows/cols 0)
  __shared__ float deg[NN];
  __shared__ float alphas[2][NB];
  __shared__ float tvals[NB];

  const int tid  = threadIdx.x;
  const int b    = blockIdx.x;
  const int lane = tid & 63;
  const int wv   = tid >> 6;

  // ---------- r1: raw a = clip(clip(adj,0,1)+I, 1e-8, inf); temps; zero W and G ----------
  if (tid < NN * NN) {
    int n = tid / NN, m = tid - n * NN;
    float v = adj[tid];
    v = fminf(fmaxf(v, 0.0f), 1.0f);
    if (n == m) v += 1.0f;
    As[n][m] = fmaxf(v, 1e-8f);
    ((float*)G)[tid] = 0.0f;                   // layer-0 P1 atomics start from 0
  }
  if (tid < NB) tvals[tid] = fminf(fmaxf(btemps[tid], 0.1f), 10.0f);
  for (int i = tid; i < 32 * WPAD / 2; i += NTHR) {
    ((unsigned*)Wh)[i] = 0u;
  }
  __syncthreads();

  // ---------- r2: adjacency degree norm; fusion alphas ----------
  if (tid < NN) {
    float s = 0.0f;
    for (int m = 0; m < NN; ++m) s += As[tid][m];
    s = fmaxf(s, 1e-8f);
    deg[tid] = fminf(fmaxf(1.0f / sqrtf(s), 0.0f), 100.0f);
  }
  if (tid == 0) {
    for (int l = 0; l < 2; ++l) {
      float l0 = flogits[l*NB+0], l1 = flogits[l*NB+1], l2 = flogits[l*NB+2];
      float mx = fmaxf(l0, fmaxf(l1, l2));
      float e0 = __expf(l0-mx), e1 = __expf(l1-mx), e2 = __expf(l2-mx);
      float s = e0 + e1 + e2;
      alphas[l][0] = e0/s; alphas[l][1] = e1/s; alphas[l][2] = e2/s;
    }
  }
  __syncthreads();

  // ---------- r3: A = d*a*d; stage x0 as bf16 into subtiled xs; zero pad rows ----------
  if (tid < NN * NN) {
    int n = tid / NN, m = tid - n * NN;
    As[n][m] = deg[n] * As[n][m] * deg[m];
  }
  #pragma unroll
  for (int j = 0; j < 11; ++j) {
    int f4  = tid + j * NTHR;
    int t   = f4 / (NN * (CC/4));
    int rem = f4 - t * (NN * (CC/4));
    int n   = rem >> 4;
    int c4  = rem & 15;
    const float4 v = *(const float4*)(&x[(size_t)b * (TT*NN*CC) + (size_t)f4 * 4]);
    uint2 p; p.x = pack2(v.x, v.y); p.y = pack2(v.z, v.w);
    *(uint2*)(&xs[xoff(n, t * 64 + c4 * 4)]) = p;
  }
  {
    int m  = 22 + (tid >> 8);
    int d0 = (tid & 255) * 4;
    *(uint2*)(&xs[xoff(m, d0)]) = make_uint2(0u, 0u);
  }
  __syncthreads();

  const unsigned xsb = (unsigned)(unsigned long long)(void*)&xs[0]; // LDS byte offset (aperture 4GB-aligned)

  // ---------- two GNN layers ----------
  for (int layer = 0; layer < 2; ++layer) {
    const int K = (layer == 0) ? 10 : 3;

    // --- P1: Gram, 32x32x16 MFMA, K=1024 over ALL 8 waves (8 steps each), ds_add reduce ---
    {
      int row = lane & 31; if (row > NN-1) row = NN-1;
      const int hi = lane >> 5;
      f32x16 acc0 = {}, acc1 = {};
      #pragma unroll
      for (int s = 0; s < 8; ++s) {
        int d0 = (wv * 8 + s) * 16 + hi * 8;
        bf16x8 a = *(const bf16x8*)(&xs[xoff(row, d0)]);
        if (s & 1) acc1 = __builtin_amdgcn_mfma_f32_32x32x16_bf16(a, a, acc1, 0, 0, 0);
        else       acc0 = __builtin_amdgcn_mfma_f32_32x32x16_bf16(a, a, acc0, 0, 0, 0);
      }
      #pragma unroll
      for (int r = 0; r < 16; ++r) {
        float vv = acc0[r] + acc1[r];
        int orow = (r & 3) + 8 * (r >> 2) + 4 * hi;
        int ocol = lane & 31;
        if (orow < NN && ocol < NN) atomicAdd(&G[orow][ocol], vv);
      }
    }
    __syncthreads();

    // --- P5big: per-thread sim-row from G (cos norms inline), rank top-K, exp -> attB ---
    if (tid < NN * NN) {
      const int n = tid / NN, m = tid - n * NN;
      const float gnn = G[n][n];
      const float rn  = 1.0f / (sqrtf(gnn) + 1e-6f);
      float simrow[NN];
      #pragma unroll
      for (int jj = 0; jj < NN / 2; ++jj) {
        const float2 g2 = *(const float2*)(&G[n][2 * jj]);
        const float2 a2 = *(const float2*)(&As[n][2 * jj]);
        const float d0  = G[2 * jj][2 * jj];
        const float d1  = G[2 * jj + 1][2 * jj + 1];
        const float r0  = 1.0f / (sqrtf(d0) + 1e-6f);
        const float r1  = 1.0f / (sqrtf(d1) + 1e-6f);
        simrow[2 * jj]     = g2.x * rn * r0 * a2.x;
        simrow[2 * jj + 1] = g2.y * rn * r1 * a2.y;
      }
      float simn = 0.f, simm = 0.f, rmax_ex = -1e30f;
      #pragma unroll
      for (int j = 0; j < NN; ++j) {
        float s = simrow[j];
        simn = (j == n) ? s : simn;
        simm = (j == m) ? s : simm;
        rmax_ex = (j == n) ? rmax_ex : fmaxf(rmax_ex, s);
      }
      #pragma unroll
      for (int k = 0; k < NB; ++k) {
        const float tk  = tvals[k];
        const float rtk = 1.0f / tk;
        const float vn  = simn + 0.1f * tk;         // t-scaled diag value
        const float vown = (m == n) ? vn : simm;
        int rank = 0;
        #pragma unroll
        for (int j = 0; j < NN; ++j) {
          float vj = (j == n) ? vn : simrow[j];
          rank += (vj > vown) || (vj == vown && j < m);
        }
        const float mxf  = fmaxf(fmaxf(rmax_ex, vn) * rtk, 0.0f);  // row max (top-1 in set)
        const float aown = (rank < K) ? vown * rtk : 0.0f;          // zeros join softmax
        attB[k][n][m] = __expf(aown - mxf);
      }
    }
    __syncthreads();

    // --- P7big: per-thread denominators (broadcast row reads) + combine -> Wh; zero G ---
    if (tid < NN * NN) {
      const int n = tid / NN, m = tid - n * NN;
      float s0 = 0.f, s1 = 0.f, s2 = 0.f;
      #pragma unroll
      for (int jj = 0; jj < NN / 2; ++jj) {
        const float2 p0 = *(const float2*)(&attB[0][n][2 * jj]);
        const float2 p1 = *(const float2*)(&attB[1][n][2 * jj]);
        const float2 p2 = *(const float2*)(&attB[2][n][2 * jj]);
        s0 += p0.x + p0.y;
        s1 += p1.x + p1.y;
        s2 += p2.x + p2.y;
      }
      const float w = attB[0][n][m] * (alphas[layer][0] / s0)
                    + attB[1][n][m] * (alphas[layer][1] / s1)
                    + attB[2][n][m] * (alphas[layer][2] / s2);
      Wh[n][m] = (unsigned short)bf16rne(w);
      ((float*)G)[tid] = 0.0f;                 // ready for next layer's P1 atomics
    }
    __syncthreads();

    // --- P8: Y^T tiles via mfma(Xt-frag(tr_read), W-frag). Wave owns 4 disjoint 32-d tiles ---
    {
      const int n_b = lane & 31;                     // output col (n), W B-frag row
      const int ko  = (lane >> 5) * 8;               // k-octet within 16-chunk
      bf16x8 w0h = *(const bf16x8*)(&Wh[n_b][ko]);
      bf16x8 w1h = *(const bf16x8*)(&Wh[n_b][16 + ko]);
      const int dpr     = lane & 31;                 // d' within 32-d tile (A-frag row)
      const int dsub_in = dpr >> 4;
      const int dcol    = dpr & 15;
      const int hi5     = lane >> 5;
      unsigned mqA  = (unsigned)(hi5 * 2);           // chunk0 m-quads: mqA, mqA+1 (0..3, real)
      unsigned mqB0 = 4 + mqA;  if (mqB0 > 5) mqB0 = 5;   // chunk1 quads, clamp to zero-padded rows
      unsigned mqB1 = 5 + mqA;  if (mqB1 > 5) mqB1 = 5;
      #pragma unroll
      for (int i = 0; i < 4; ++i) {
        const int dtile = wv * 4 + i;
        const unsigned rowb = xsb + (unsigned)(dtile * 2 + dsub_in) * 6u * 128u + (unsigned)dcol * 8u;
        unsigned long long t00, t01, t10, t11;
        asm volatile("ds_read_b64_tr_b16 %0, %1" : "=v"(t00) : "v"(rowb + mqA * 128u));
        asm volatile("ds_read_b64_tr_b16 %0, %1" : "=v"(t01) : "v"(rowb + (mqA + 1u) * 128u));
        asm volatile("ds_read_b64_tr_b16 %0, %1" : "=v"(t10) : "v"(rowb + mqB0 * 128u));
        asm volatile("ds_read_b64_tr_b16 %0, %1" : "=v"(t11) : "v"(rowb + mqB1 * 128u));
        asm volatile("s_waitcnt lgkmcnt(0)" ::: "memory");
        __builtin_amdgcn_sched_barrier(0);
        int4 a0i = make_int4((int)t00, (int)(t00 >> 32), (int)t01, (int)(t01 >> 32));
        int4 a1i = make_int4((int)t10, (int)(t10 >> 32), (int)t11, (int)(t11 >> 32));
        bf16x8 A0 = __builtin_bit_cast(bf16x8, a0i);
        bf16x8 A1 = __builtin_bit_cast(bf16x8, a1i);
        f32x16 acc = {};
        acc = __builtin_amdgcn_mfma_f32_32x32x16_bf16(A0, w0h, acc, 0, 0, 0);
        acc = __builtin_amdgcn_mfma_f32_32x32x16_bf16(A1, w1h, acc, 0, 0, 0);
        if (n_b < NN) {
          if (layer == 0) {
            #pragma unroll
            for (int q = 0; q < 4; ++q) {
              int dq = dtile * 32 + 4 * hi5 + 8 * q;
              uint2 p;
              p.x = pack2(fmaxf(acc[4*q+0], 0.f), fmaxf(acc[4*q+1], 0.f));
              p.y = pack2(fmaxf(acc[4*q+2], 0.f), fmaxf(acc[4*q+3], 0.f));
              *(uint2*)(&xs[xoff(n_b, dq)]) = p;     // own d-tile: no cross-wave race
            }
          } else {
            #pragma unroll
            for (int q = 0; q < 4; ++q) {
              int dq = dtile * 32 + 4 * hi5 + 8 * q;
              int t = dq >> 6, c = dq & 63;
              const float4 r = *(const float4*)(&x[(size_t)b * (TT*NN*CC) + (t * NN + n_b) * CC + c]);
              float4 o = make_float4(acc[4*q+0] + r.x, acc[4*q+1] + r.y,
                                     acc[4*q+2] + r.z, acc[4*q+3] + r.w);
              *(float4*)(&out[((size_t)b * NN + n_b) * DD + dq]) = o;
            }
          }
        }
      }
    }
    if (layer == 0) __syncthreads();   // layer-1 epilogue: nothing after reads P8's outputs
  }

  // ---------- A output (second tuple element) ----------
  if (b == 0 && tid < NN * NN) {
    out[(size_t)BATCH * NN * DD + tid] = As[tid / NN][tid - (tid / NN) * NN];
  }
}

extern "C" void kernel_launch(void* const* d_in, const int* in_sizes, int n_in,
                              void* d_out, int out_size, void* d_ws, size_t ws_size,
                              hipStream_t stream) {
  const float* x       = (const float*)d_in[0];
  const float* adj     = (const float*)d_in[1];
  const float* btemps  = (const float*)d_in[2];
  const float* flogits = (const float*)d_in[3];
  float* out = (float*)d_out;
  mbdsca_fused<<<BATCH, NTHR, 0, stream>>>(x, adj, btemps, flogits, out);
}

// Round 17
// 50.822 us; speedup vs baseline: 1.5711x; 1.5711x over previous
//
#include <hip/hip_runtime.h>
#include <hip/hip_bf16.h>

#define BATCH  512
#define TT     16
#define NN     22
#define CC     64
#define DD     1024          // TT*CC
#define NB     3
#define NTHR   512
#define WPAD   40            // Wh row stride (u16): 80B rows, 16B-aligned

typedef __bf16 bf16x8 __attribute__((ext_vector_type(8)));
typedef float  f32x4  __attribute__((ext_vector_type(4)));
typedef float  f32x16 __attribute__((ext_vector_type(16)));

__device__ __forceinline__ unsigned bf16rne(float x) {
  unsigned u = __float_as_uint(x);
  u += 0x7fffu + ((u >> 16) & 1u);
  return u >> 16;
}
__device__ __forceinline__ unsigned pack2(float a, float b) {
  return bf16rne(a) | (bf16rne(b) << 16);
}
// xs subtiled layout: 128B blocks of [4 m][16 d] bf16, block index (d>>4)*6 + (m>>2)
__device__ __forceinline__ unsigned xoff(unsigned m, unsigned d) {
  return ((d >> 4) * 6u + (m >> 2)) * 64u + (m & 3u) * 16u + (d & 15u);
}

__global__ __launch_bounds__(NTHR) void mbdsca_fused(
    const float* __restrict__ x,        // [B, T, N, C]
    const float* __restrict__ adj,      // [N, N]
    const float* __restrict__ btemps,   // [NB]
    const float* __restrict__ flogits,  // [2, NB]
    float* __restrict__ out)            // [B*N*D] xb ++ [N*N] A
{
  __shared__ unsigned short xs[6 * 64 * 64];   // 49152 B, 24 m-rows (22 real + 2 zero)
  __shared__ float As[NN][NN];
  __shared__ float Gp[8][NN][NN];              // Gram K-split partials (8 waves)
  __shared__ float simS[NN][NN];
  __shared__ float attB[NB][NN][NN];
  __shared__ float mxs[NB][NN];
  __shared__ float sinv[NB][NN];
  __shared__ unsigned short Wh[32][WPAD];      // combined weights, bf16 (pad rows/cols 0)
  __shared__ float deg[NN];
  __shared__ float alphas[2][NB];
  __shared__ float tvals[NB];

  const int tid  = threadIdx.x;
  const int b    = blockIdx.x;
  const int lane = tid & 63;
  const int wv   = tid >> 6;

  // ---------- region 1: raw a = clip(clip(adj,0,1)+I, 1e-8, inf); temps; zero W ----------
  if (tid < NN * NN) {
    int n = tid / NN, m = tid - n * NN;
    float v = adj[tid];
    v = fminf(fmaxf(v, 0.0f), 1.0f);
    if (n == m) v += 1.0f;
    As[n][m] = fmaxf(v, 1e-8f);
  }
  if (tid < NB) tvals[tid] = fminf(fmaxf(btemps[tid], 0.1f), 10.0f);
  for (int i = tid; i < 32 * WPAD / 2; i += NTHR) {
    ((unsigned*)Wh)[i] = 0u;
  }
  __syncthreads();

  // ---------- region 2: adjacency degree norm; fusion alphas ----------
  if (tid < NN) {
    float s = 0.0f;
    for (int m = 0; m < NN; ++m) s += As[tid][m];
    s = fmaxf(s, 1e-8f);
    deg[tid] = fminf(fmaxf(1.0f / sqrtf(s), 0.0f), 100.0f);
  }
  if (tid == 0) {
    for (int l = 0; l < 2; ++l) {
      float l0 = flogits[l*NB+0], l1 = flogits[l*NB+1], l2 = flogits[l*NB+2];
      float mx = fmaxf(l0, fmaxf(l1, l2));
      float e0 = __expf(l0-mx), e1 = __expf(l1-mx), e2 = __expf(l2-mx);
      float s = e0 + e1 + e2;
      alphas[l][0] = e0/s; alphas[l][1] = e1/s; alphas[l][2] = e2/s;
    }
  }
  __syncthreads();

  // ---------- region 3: A = d*a*d; stage x0 as bf16 into subtiled xs; zero pad rows ----------
  if (tid < NN * NN) {
    int n = tid / NN, m = tid - n * NN;
    As[n][m] = deg[n] * As[n][m] * deg[m];
  }
  #pragma unroll
  for (int j = 0; j < 11; ++j) {
    int f4  = tid + j * NTHR;
    int t   = f4 / (NN * (CC/4));
    int rem = f4 - t * (NN * (CC/4));
    int n   = rem >> 4;
    int c4  = rem & 15;
    const float4 v = *(const float4*)(&x[(size_t)b * (TT*NN*CC) + (size_t)f4 * 4]);
    uint2 p; p.x = pack2(v.x, v.y); p.y = pack2(v.z, v.w);
    *(uint2*)(&xs[xoff(n, t * 64 + c4 * 4)]) = p;
  }
  {
    int m  = 22 + (tid >> 8);
    int d0 = (tid & 255) * 4;
    *(uint2*)(&xs[xoff(m, d0)]) = make_uint2(0u, 0u);
  }
  __syncthreads();

  // ---------- A output (second tuple element): As is final; overlap with layer-0 compute ----------
  if (b == 0 && tid < NN * NN) {
    out[(size_t)BATCH * NN * DD + tid] = As[tid / NN][tid - (tid / NN) * NN];
  }

  const unsigned xsb = (unsigned)(unsigned long long)(void*)&xs[0]; // LDS byte offset (aperture 4GB-aligned)

  // ---------- two GNN layers ----------
  for (int layer = 0; layer < 2; ++layer) {
    const int K = (layer == 0) ? 10 : 3;

    // --- P1: Gram partials, 32x32x16 MFMA, K=1024 split over ALL 8 waves (8 steps each) ---
    {
      int row = lane & 31; if (row > NN-1) row = NN-1;
      const int hi = lane >> 5;
      f32x16 acc0 = {}, acc1 = {};
      #pragma unroll
      for (int s = 0; s < 8; ++s) {
        int d0 = (wv * 8 + s) * 16 + hi * 8;
        bf16x8 a = *(const bf16x8*)(&xs[xoff(row, d0)]);
        if (s & 1) acc1 = __builtin_amdgcn_mfma_f32_32x32x16_bf16(a, a, acc1, 0, 0, 0);
        else       acc0 = __builtin_amdgcn_mfma_f32_32x32x16_bf16(a, a, acc0, 0, 0, 0);
      }
      #pragma unroll
      for (int r = 0; r < 16; ++r) {
        float vv = acc0[r] + acc1[r];
        int orow = (r & 3) + 8 * (r >> 2) + 4 * hi;
        int ocol = lane & 31;
        if (orow < NN && ocol < NN) Gp[wv][orow][ocol] = vv;
      }
    }
    __syncthreads();

    // --- P3': sum 8 partials, per-thread cosine norms, sim = g*rn*rm*A -> simS ---
    if (tid < NN * NN) {
      int n = tid / NN, m = tid - n * NN;
      float g  = ((Gp[0][n][m] + Gp[1][n][m]) + (Gp[2][n][m] + Gp[3][n][m]))
               + ((Gp[4][n][m] + Gp[5][n][m]) + (Gp[6][n][m] + Gp[7][n][m]));
      float gn = ((Gp[0][n][n] + Gp[1][n][n]) + (Gp[2][n][n] + Gp[3][n][n]))
               + ((Gp[4][n][n] + Gp[5][n][n]) + (Gp[6][n][n] + Gp[7][n][n]));
      float gm = ((Gp[0][m][m] + Gp[1][m][m]) + (Gp[2][m][m] + Gp[3][m][m]))
               + ((Gp[4][m][m] + Gp[5][m][m]) + (Gp[6][m][m] + Gp[7][m][m]));
      float rn = 1.0f / (sqrtf(gn) + 1e-6f);
      float rm = 1.0f / (sqrtf(gm) + 1e-6f);
      simS[n][m] = g * rn * rm * As[n][m];
    }
    __syncthreads();

    // --- P5: row in registers; top-K mask via rank (lax.top_k tie rule) for all 3 branches ---
    if (tid < NN * NN) {
      const int n = tid / NN, m = tid - n * NN;
      float simrow[NN];
      float simn = 0.f, simm = 0.f, rmax_ex = -1e30f;
      #pragma unroll
      for (int j = 0; j < NN; ++j) {
        float s = simS[n][j];
        simrow[j] = s;
        simn = (j == n) ? s : simn;
        simm = (j == m) ? s : simm;
        rmax_ex = (j == n) ? rmax_ex : fmaxf(rmax_ex, s);
      }
      #pragma unroll
      for (int k = 0; k < NB; ++k) {
        const float tk  = tvals[k];
        const float rtk = 1.0f / tk;
        const float vn  = simn + 0.1f * tk;         // t-scaled diag value
        const float vown = (m == n) ? vn : simm;
        int rank = 0;
        #pragma unroll
        for (int j = 0; j < NN; ++j) {
          float vj = (j == n) ? vn : simrow[j];
          rank += (vj > vown) || (vj == vown && j < m);
        }
        attB[k][n][m] = (rank < K) ? vown * rtk : 0.0f;   // zeros still join softmax
        if (m == 0) mxs[k][n] = fmaxf(fmaxf(rmax_ex, vn) * rtk, 0.0f);
      }
    }
    __syncthreads();

    // --- P6: softmax denominators ---
    if (tid < NB * NN) {
      int k = tid / NN, n = tid - k * NN;
      float mx = mxs[k][n], s = 0.0f;
      #pragma unroll
      for (int m2 = 0; m2 < NN; ++m2) s += __expf(attB[k][n][m2] - mx);
      sinv[k][n] = alphas[layer][k] / s;
    }
    __syncthreads();

    // --- P7: combined weights -> bf16 ---
    if (tid < NN * NN) {
      int n = tid / NN, m = tid - n * NN;
      float w = 0.0f;
      #pragma unroll
      for (int k = 0; k < NB; ++k)
        w += __expf(attB[k][n][m] - mxs[k][n]) * sinv[k][n];
      Wh[n][m] = (unsigned short)bf16rne(w);
    }
    __syncthreads();

    // --- P8: Y^T tiles via mfma(Xt-frag(tr_read), W-frag). Wave owns 4 disjoint 32-d tiles ---
    {
      const int n_b = lane & 31;                     // output col (n), W B-frag row
      const int ko  = (lane >> 5) * 8;               // k-octet within 16-chunk
      bf16x8 w0h = *(const bf16x8*)(&Wh[n_b][ko]);
      bf16x8 w1h = *(const bf16x8*)(&Wh[n_b][16 + ko]);
      const int dpr     = lane & 31;                 // d' within 32-d tile (A-frag row)
      const int dsub_in = dpr >> 4;
      const int dcol    = dpr & 15;
      const int hi5     = lane >> 5;
      unsigned mqA  = (unsigned)(hi5 * 2);           // chunk0 m-quads: mqA, mqA+1 (0..3, real)
      unsigned mqB0 = 4 + mqA;  if (mqB0 > 5) mqB0 = 5;   // chunk1 quads, clamp to zero-padded rows
      unsigned mqB1 = 5 + mqA;  if (mqB1 > 5) mqB1 = 5;
      #pragma unroll
      for (int i = 0; i < 4; ++i) {
        const int dtile = wv * 4 + i;
        const unsigned rowb = xsb + (unsigned)(dtile * 2 + dsub_in) * 6u * 128u + (unsigned)dcol * 8u;
        unsigned long long t00, t01, t10, t11;
        asm volatile("ds_read_b64_tr_b16 %0, %1" : "=v"(t00) : "v"(rowb + mqA * 128u));
        asm volatile("ds_read_b64_tr_b16 %0, %1" : "=v"(t01) : "v"(rowb + (mqA + 1u) * 128u));
        asm volatile("ds_read_b64_tr_b16 %0, %1" : "=v"(t10) : "v"(rowb + mqB0 * 128u));
        asm volatile("ds_read_b64_tr_b16 %0, %1" : "=v"(t11) : "v"(rowb + mqB1 * 128u));
        asm volatile("s_waitcnt lgkmcnt(0)" ::: "memory");
        __builtin_amdgcn_sched_barrier(0);
        int4 a0i = make_int4((int)t00, (int)(t00 >> 32), (int)t01, (int)(t01 >> 32));
        int4 a1i = make_int4((int)t10, (int)(t10 >> 32), (int)t11, (int)(t11 >> 32));
        bf16x8 A0 = __builtin_bit_cast(bf16x8, a0i);
        bf16x8 A1 = __builtin_bit_cast(bf16x8, a1i);
        f32x16 acc = {};
        acc = __builtin_amdgcn_mfma_f32_32x32x16_bf16(A0, w0h, acc, 0, 0, 0);
        acc = __builtin_amdgcn_mfma_f32_32x32x16_bf16(A1, w1h, acc, 0, 0, 0);
        if (n_b < NN) {
          if (layer == 0) {
            #pragma unroll
            for (int q = 0; q < 4; ++q) {
              int dq = dtile * 32 + 4 * hi5 + 8 * q;
              uint2 p;
              p.x = pack2(fmaxf(acc[4*q+0], 0.f), fmaxf(acc[4*q+1], 0.f));
              p.y = pack2(fmaxf(acc[4*q+2], 0.f), fmaxf(acc[4*q+3], 0.f));
              *(uint2*)(&xs[xoff(n_b, dq)]) = p;     // own d-tile: no cross-wave race
            }
          } else {
            #pragma unroll
            for (int q = 0; q < 4; ++q) {
              int dq = dtile * 32 + 4 * hi5 + 8 * q;
              int t = dq >> 6, c = dq & 63;
              const float4 r = *(const float4*)(&x[(size_t)b * (TT*NN*CC) + (t * NN + n_b) * CC + c]);
              float4 o = make_float4(acc[4*q+0] + r.x, acc[4*q+1] + r.y,
                                     acc[4*q+2] + r.z, acc[4*q+3] + r.w);
              *(float4*)(&out[((size_t)b * NN + n_b) * DD + dq]) = o;
            }
          }
        }
      }
    }
    if (layer == 0) __syncthreads();   // layer-1 epilogue: nothing after reads P8's outputs
  }
}

extern "C" void kernel_launch(void* const* d_in, const int* in_sizes, int n_in,
                              void* d_out, int out_size, void* d_ws, size_t ws_size,
                              hipStream_t stream) {
  const float* x       = (const float*)d_in[0];
  const float* adj     = (const float*)d_in[1];
  const float* btemps  = (const float*)d_in[2];
  const float* flogits = (const float*)d_in[3];
  float* out = (float*)d_out;
  mbdsca_fused<<<BATCH, NTHR, 0, stream>>>(x, adj, btemps, flogits, out);
}